// Round 2
// 279.425 us; speedup vs baseline: 1.0156x; 1.0156x over previous
//
#include <hip/hip_runtime.h>
#include <math.h>

// mLSTM cell, B=128, I=512, H=512.
// Outputs concatenated: h_t[128*512], C_t[128*512*512], m_t[128*512], n_t[128*512]
//
// ws layout (floats):
//   gates  : 128*3072 = 393216 @ 0
//   f_arr  : 65536 @ 393216
//   add_arr: 65536 @ 458752
//   o_arr  : 65536 @ 524288
//   invden : 128   @ 589824
// total ~2.36 MB

#define B_SZ   128
#define H_DIM  512
#define I_DIM  512
#define G6     3072           // 6*H
#define BH     65536          // B*H
#define CSZ    33554432       // B*H*H

// native vector type for nontemporal builtins (HIP float4 is a class -> rejected)
typedef float f32x4 __attribute__((ext_vector_type(4)));

// ---------------- Kernel 1: gates = x @ W^T + b ----------------
// c-tile = 256 (one column per thread), b-tile = 4 (register-blocked).
// Grid = 12 c-tiles * 32 b-tiles = 384 blocks -> ~1.5 blocks/CU, 6 waves/CU
// (was 192 blocks = 1 wave/SIMD, fully latency-exposed).
// x addresses are wave-uniform -> scalar loads; W is per-thread sequential float4.
__global__ __launch_bounds__(256) void gemm_gates(
    const float* __restrict__ x, const float* __restrict__ W,
    const float* __restrict__ bias, float* __restrict__ gates) {
  const int tid = threadIdx.x;
  const int c   = (blockIdx.x % 12) * 256 + tid;   // [0, 3072)
  const int b0  = (blockIdx.x / 12) * 4;           // [0, 128) step 4

  float acc[4];
#pragma unroll
  for (int j = 0; j < 4; ++j) acc[j] = 0.0f;

  const float4* wrow = reinterpret_cast<const float4*>(W + (size_t)c * I_DIM);
  const float4* x4   = reinterpret_cast<const float4*>(x);

#pragma unroll 2
  for (int t4 = 0; t4 < I_DIM / 4; ++t4) {
    const float4 wv = wrow[t4];
#pragma unroll
    for (int j = 0; j < 4; ++j) {
      const float4 xv = x4[(b0 + j) * (I_DIM / 4) + t4];   // uniform addr -> s_load
      acc[j] += xv.x * wv.x + xv.y * wv.y + xv.z * wv.z + xv.w * wv.w;
    }
  }
  const float bi = bias[c];
#pragma unroll
  for (int j = 0; j < 4; ++j)
    gates[(size_t)(b0 + j) * G6 + c] = acc[j] + bi;   // coalesced over c
}

// ---------------- Kernel 2: pointwise gate math + nq reduction ----------------
// One block per batch row b, 512 threads = one h per thread, single pass.
__global__ __launch_bounds__(512) void gate_pointwise(
    const float* __restrict__ gates, const float* __restrict__ m_prev,
    const float* __restrict__ n_prev, float* __restrict__ out,
    float* __restrict__ f_arr, float* __restrict__ add_arr,
    float* __restrict__ o_arr, float* __restrict__ invden) {
  const int b = blockIdx.x;
  const int h = threadIdx.x;                       // [0, 512)
  const float inv_sqrt_h = 0.044194173824159216f;  // 1/sqrt(512)

  const float* g = gates + (size_t)b * G6;
  float* out_m = out + BH + CSZ;
  float* out_n = out_m + BH;

  const float ig = g[h];
  const float fg = g[512 + h];
  const float og = g[1024 + h];
  const float q  = g[1536 + h];
  const float k  = g[2048 + h];
  const float v  = g[2560 + h];

  const int   idx = b * H_DIM + h;
  const float kt  = inv_sqrt_h * k;
  const float ot  = 1.0f / (1.0f + expf(-og));
  const float mp  = m_prev[idx];
  const float npv = n_prev[idx];
  const float mt  = fmaxf(fg + mp, ig);
  const float it  = expf(ig - mt);
  const float ft  = expf(fg + mp - mt);    // arg <= 0, no overflow
  const float nt  = ft * npv + it * kt;

  out_m[idx]   = mt;
  out_n[idx]   = nt;
  f_arr[idx]   = ft;
  add_arr[idx] = it * v * kt;
  o_arr[idx]   = ot;

  __shared__ float red[512];
  red[h] = nt * q;
  __syncthreads();
#pragma unroll
  for (int s = 256; s > 0; s >>= 1) {
    if (h < s) red[h] += red[h + s];
    __syncthreads();
  }
  if (h == 0) {
    const float denom = fmaxf(fabsf(red[0]), 1e-6f);
    invden[b] = 1.0f / denom;
  }
}

// ---------------- Kernel 3: C_t = f*C_prev + add; Cq; h_t ----------------
// 2048 persistent blocks x 256 threads; each block owns 32 consecutive rows
// (all in the same batch b since 32 | 512), one row per wave per iteration.
// q[b,:] hoisted into registers once per block; C stream uses nontemporal
// loads/stores (single-use 134 MB each way -> don't churn L2).
__global__ __launch_bounds__(256) void update_C(
    const float* __restrict__ C_prev, const float* __restrict__ gates,
    const float* __restrict__ f_arr, const float* __restrict__ add_arr,
    const float* __restrict__ o_arr, const float* __restrict__ invden,
    float* __restrict__ out) {
  const int tid  = threadIdx.x;
  const int lane = tid & 63;
  const int w    = tid >> 6;
  const int r0   = blockIdx.x * 32;     // 32 rows per block, block-uniform b
  const int b    = r0 >> 9;

  const float4* q4 = reinterpret_cast<const float4*>(gates + (size_t)b * G6 + 1536);
  const float4 qa = q4[lane];
  const float4 qb = q4[lane + 64];
  const float inv_d = invden[b];

#pragma unroll 2
  for (int it = 0; it < 8; ++it) {
    const int r = r0 + it * 4 + w;
    const float f = f_arr[r];
    const float a = add_arr[r];

    const f32x4* cp = reinterpret_cast<const f32x4*>(C_prev) + (size_t)r * 128;
    f32x4*       ct = reinterpret_cast<f32x4*>((float*)out + BH) + (size_t)r * 128;

    const f32x4 c0 = __builtin_nontemporal_load(cp + lane);
    const f32x4 c1 = __builtin_nontemporal_load(cp + lane + 64);

    f32x4 o0, o1;
    o0.x = f * c0.x + a;  o0.y = f * c0.y + a;
    o0.z = f * c0.z + a;  o0.w = f * c0.w + a;
    o1.x = f * c1.x + a;  o1.y = f * c1.y + a;
    o1.z = f * c1.z + a;  o1.w = f * c1.w + a;

    __builtin_nontemporal_store(o0, ct + lane);
    __builtin_nontemporal_store(o1, ct + lane + 64);

    float cq = o0.x * qa.x + o0.y * qa.y + o0.z * qa.z + o0.w * qa.w
             + o1.x * qb.x + o1.y * qb.y + o1.z * qb.z + o1.w * qb.w;
#pragma unroll
    for (int off = 32; off > 0; off >>= 1)
      cq += __shfl_xor(cq, off, 64);
    if (lane == 0)
      out[r] = o_arr[r] * cq * inv_d;
  }
}

extern "C" void kernel_launch(void* const* d_in, const int* in_sizes, int n_in,
                              void* d_out, int out_size, void* d_ws, size_t ws_size,
                              hipStream_t stream) {
  const float* x      = (const float*)d_in[0];
  // d_in[1] = h_prev (unused by the reference computation)
  const float* C_prev = (const float*)d_in[2];
  const float* m_prev = (const float*)d_in[3];
  const float* n_prev = (const float*)d_in[4];
  const float* W      = (const float*)d_in[5];
  const float* bias   = (const float*)d_in[6];

  float* out = (float*)d_out;
  float* ws  = (float*)d_ws;

  float* gates   = ws;
  float* f_arr   = ws + 393216;
  float* add_arr = f_arr + BH;
  float* o_arr   = add_arr + BH;
  float* invden  = o_arr + BH;

  gemm_gates<<<384, 256, 0, stream>>>(x, W, bias, gates);
  gate_pointwise<<<B_SZ, 512, 0, stream>>>(gates, m_prev, n_prev, out,
                                           f_arr, add_arr, o_arr, invden);
  update_C<<<BH / 32, 256, 0, stream>>>(C_prev, gates, f_arr, add_arr, o_arr,
                                        invden, out);
}

// Round 3
// 275.787 us; speedup vs baseline: 1.0290x; 1.0132x over previous
//
#include <hip/hip_runtime.h>
#include <math.h>

// mLSTM cell, B=128, I=512, H=512.
// Outputs concatenated: h_t[128*512], C_t[128*512*512], m_t[128*512], n_t[128*512]
//
// ws layout (floats):
//   gates  : 128*3072 = 393216 @ 0
//   f_arr  : 65536 @ 393216
//   add_arr: 65536 @ 458752
//   o_arr  : 65536 @ 524288
//   invden : 128   @ 589824
// total ~2.36 MB

#define B_SZ   128
#define H_DIM  512
#define I_DIM  512
#define G6     3072           // 6*H
#define BH     65536          // B*H
#define CSZ    33554432       // B*H*H

// native vector type for nontemporal builtins (HIP float4 is a class -> rejected)
typedef float f32x4 __attribute__((ext_vector_type(4)));

// ---------------- Kernel 1: gates = x @ W^T + b ----------------
// c-tile = 256 (one column per thread), b-tile = 4 (register-blocked).
// Grid = 12 c-tiles * 32 b-tiles = 384 blocks (~1.5 blocks/CU, 6 waves/CU).
// Only ~1.5 waves/SIMD -> ILP must hide latency: unroll 4 keeps 4 W-float4
// loads + 16 scalar x-loads in flight.
// x addresses are wave-uniform -> scalar loads; W is per-thread sequential float4.
__global__ __launch_bounds__(256) void gemm_gates(
    const float* __restrict__ x, const float* __restrict__ W,
    const float* __restrict__ bias, float* __restrict__ gates) {
  const int tid = threadIdx.x;
  const int c   = (blockIdx.x % 12) * 256 + tid;   // [0, 3072)
  const int b0  = (blockIdx.x / 12) * 4;           // [0, 128) step 4

  float acc[4];
#pragma unroll
  for (int j = 0; j < 4; ++j) acc[j] = 0.0f;

  const float4* wrow = reinterpret_cast<const float4*>(W + (size_t)c * I_DIM);
  const float4* x4   = reinterpret_cast<const float4*>(x);

#pragma unroll 4
  for (int t4 = 0; t4 < I_DIM / 4; ++t4) {
    const float4 wv = wrow[t4];
#pragma unroll
    for (int j = 0; j < 4; ++j) {
      const float4 xv = x4[(b0 + j) * (I_DIM / 4) + t4];   // uniform addr -> s_load
      acc[j] += xv.x * wv.x + xv.y * wv.y + xv.z * wv.z + xv.w * wv.w;
    }
  }
  const float bi = bias[c];
#pragma unroll
  for (int j = 0; j < 4; ++j)
    gates[(size_t)(b0 + j) * G6 + c] = acc[j] + bi;   // coalesced over c
}

// ---------------- Kernel 2: pointwise gate math + nq reduction ----------------
// One block per batch row b, 512 threads = one h per thread, single pass.
__global__ __launch_bounds__(512) void gate_pointwise(
    const float* __restrict__ gates, const float* __restrict__ m_prev,
    const float* __restrict__ n_prev, float* __restrict__ out,
    float* __restrict__ f_arr, float* __restrict__ add_arr,
    float* __restrict__ o_arr, float* __restrict__ invden) {
  const int b = blockIdx.x;
  const int h = threadIdx.x;                       // [0, 512)
  const float inv_sqrt_h = 0.044194173824159216f;  // 1/sqrt(512)

  const float* g = gates + (size_t)b * G6;
  float* out_m = out + BH + CSZ;
  float* out_n = out_m + BH;

  const float ig = g[h];
  const float fg = g[512 + h];
  const float og = g[1024 + h];
  const float q  = g[1536 + h];
  const float k  = g[2048 + h];
  const float v  = g[2560 + h];

  const int   idx = b * H_DIM + h;
  const float kt  = inv_sqrt_h * k;
  const float ot  = 1.0f / (1.0f + expf(-og));
  const float mp  = m_prev[idx];
  const float npv = n_prev[idx];
  const float mt  = fmaxf(fg + mp, ig);
  const float it  = expf(ig - mt);
  const float ft  = expf(fg + mp - mt);    // arg <= 0, no overflow
  const float nt  = ft * npv + it * kt;

  out_m[idx]   = mt;
  out_n[idx]   = nt;
  f_arr[idx]   = ft;
  add_arr[idx] = it * v * kt;
  o_arr[idx]   = ot;

  __shared__ float red[512];
  red[h] = nt * q;
  __syncthreads();
#pragma unroll
  for (int s = 256; s > 0; s >>= 1) {
    if (h < s) red[h] += red[h + s];
    __syncthreads();
  }
  if (h == 0) {
    const float denom = fmaxf(fabsf(red[0]), 1e-6f);
    invden[b] = 1.0f / denom;
  }
}

// ---------------- Kernel 3: C_t = f*C_prev + add; Cq; h_t ----------------
// 2048 blocks x 256 threads; each block owns 32 consecutive rows (same batch b
// since 32 | 512), one row per wave per iteration (8 iterations).
// All per-row scalars (f, add, o) hoisted to block start as independent loads
// so the streaming loop has no leading dependent-load stalls.
// q[b,:] hoisted into registers once; C stream uses nontemporal loads/stores
// (single-use 134 MB each way -> don't churn L2).
__global__ __launch_bounds__(256) void update_C(
    const float* __restrict__ C_prev, const float* __restrict__ gates,
    const float* __restrict__ f_arr, const float* __restrict__ add_arr,
    const float* __restrict__ o_arr, const float* __restrict__ invden,
    float* __restrict__ out) {
  const int tid  = threadIdx.x;
  const int lane = tid & 63;
  const int w    = tid >> 6;
  const int r0   = blockIdx.x * 32;     // 32 rows per block, block-uniform b
  const int b    = r0 >> 9;

  const float4* q4 = reinterpret_cast<const float4*>(gates + (size_t)b * G6 + 1536);
  const float4 qa = q4[lane];
  const float4 qb = q4[lane + 64];
  const float inv_d = invden[b];

  // hoist all per-row scalars (independent loads, issued together)
  float fv[8], av[8], hv[8];
#pragma unroll
  for (int it = 0; it < 8; ++it) {
    const int r = r0 + it * 4 + w;
    fv[it] = f_arr[r];
    av[it] = add_arr[r];
    hv[it] = o_arr[r];
  }

#pragma unroll
  for (int it = 0; it < 8; ++it) {
    const int r = r0 + it * 4 + w;
    const float f = fv[it];
    const float a = av[it];

    const f32x4* cp = reinterpret_cast<const f32x4*>(C_prev) + (size_t)r * 128;
    f32x4*       ct = reinterpret_cast<f32x4*>((float*)out + BH) + (size_t)r * 128;

    const f32x4 c0 = __builtin_nontemporal_load(cp + lane);
    const f32x4 c1 = __builtin_nontemporal_load(cp + lane + 64);

    f32x4 o0, o1;
    o0.x = f * c0.x + a;  o0.y = f * c0.y + a;
    o0.z = f * c0.z + a;  o0.w = f * c0.w + a;
    o1.x = f * c1.x + a;  o1.y = f * c1.y + a;
    o1.z = f * c1.z + a;  o1.w = f * c1.w + a;

    __builtin_nontemporal_store(o0, ct + lane);
    __builtin_nontemporal_store(o1, ct + lane + 64);

    float cq = o0.x * qa.x + o0.y * qa.y + o0.z * qa.z + o0.w * qa.w
             + o1.x * qb.x + o1.y * qb.y + o1.z * qb.z + o1.w * qb.w;
#pragma unroll
    for (int off = 32; off > 0; off >>= 1)
      cq += __shfl_xor(cq, off, 64);
    if (lane == 0)
      out[r] = hv[it] * cq * inv_d;
  }
}

extern "C" void kernel_launch(void* const* d_in, const int* in_sizes, int n_in,
                              void* d_out, int out_size, void* d_ws, size_t ws_size,
                              hipStream_t stream) {
  const float* x      = (const float*)d_in[0];
  // d_in[1] = h_prev (unused by the reference computation)
  const float* C_prev = (const float*)d_in[2];
  const float* m_prev = (const float*)d_in[3];
  const float* n_prev = (const float*)d_in[4];
  const float* W      = (const float*)d_in[5];
  const float* bias   = (const float*)d_in[6];

  float* out = (float*)d_out;
  float* ws  = (float*)d_ws;

  float* gates   = ws;
  float* f_arr   = ws + 393216;
  float* add_arr = f_arr + BH;
  float* o_arr   = add_arr + BH;
  float* invden  = o_arr + BH;

  gemm_gates<<<384, 256, 0, stream>>>(x, W, bias, gates);
  gate_pointwise<<<B_SZ, 512, 0, stream>>>(gates, m_prev, n_prev, out,
                                           f_arr, add_arr, o_arr, invden);
  update_C<<<BH / 32, 256, 0, stream>>>(C_prev, gates, f_arr, add_arr, o_arr,
                                        invden, out);
}

// Round 4
// 274.159 us; speedup vs baseline: 1.0351x; 1.0059x over previous
//
#include <hip/hip_runtime.h>
#include <math.h>

// mLSTM cell, B=128, I=512, H=512.
// Outputs concatenated: h_t[128*512], C_t[128*512*512], m_t[128*512], n_t[128*512]
//
// ws layout (floats):
//   gates  : 128*3072 = 393216 @ 0
//   invden : 128 @ 393216
// total ~1.6 MB

#define B_SZ   128
#define H_DIM  512
#define I_DIM  512
#define G6     3072           // 6*H
#define BH     65536          // B*H
#define CSZ    33554432       // B*H*H

// native vector type for nontemporal builtins (HIP float4 is a class -> rejected)
typedef float f32x4 __attribute__((ext_vector_type(4)));

// ---------------- Kernel 1: gates = x @ W^T + b ----------------
// 24 c-tiles x 128 columns, b-tile = 4 -> grid = 24*32 = 768 blocks x 128 thr
// (3 blocks/CU, all co-resident). XCD-aware mapping: ctile = (blk%8)*3 +
// (blk/8)%3 pins 3 c-tiles (768 KB of W) to each XCD -> the 32x b-tile
// re-reads of each W c-tile hit that XCD's 4 MiB L2 instead of LLC.
// x addresses are wave-uniform -> scalar loads; W is per-thread sequential float4.
__global__ __launch_bounds__(128) void gemm_gates(
    const float* __restrict__ x, const float* __restrict__ W,
    const float* __restrict__ bias, float* __restrict__ gates) {
  const int tid   = threadIdx.x;
  const int blk   = blockIdx.x;
  const int xcd   = blk & 7;
  const int j     = blk >> 3;            // [0, 96)
  const int ctile = xcd * 3 + (j % 3);   // [0, 24) -- 3 c-tiles per XCD
  const int btile = j / 3;               // [0, 32)
  const int c     = ctile * 128 + tid;   // [0, 3072)
  const int b0    = btile * 4;           // [0, 128) step 4

  float acc[4];
#pragma unroll
  for (int jj = 0; jj < 4; ++jj) acc[jj] = 0.0f;

  const float4* wrow = reinterpret_cast<const float4*>(W + (size_t)c * I_DIM);
  const float4* x4   = reinterpret_cast<const float4*>(x);

#pragma unroll 4
  for (int t4 = 0; t4 < I_DIM / 4; ++t4) {
    const float4 wv = wrow[t4];
#pragma unroll
    for (int jj = 0; jj < 4; ++jj) {
      const float4 xv = x4[(b0 + jj) * (I_DIM / 4) + t4];  // uniform -> s_load
      acc[jj] += xv.x * wv.x + xv.y * wv.y + xv.z * wv.z + xv.w * wv.w;
    }
  }
  const float bi = bias[c];
#pragma unroll
  for (int jj = 0; jj < 4; ++jj)
    gates[(size_t)(b0 + jj) * G6 + c] = acc[jj] + bi;  // coalesced over c
}

// ---------------- Kernel 2: m_t, n_t, invden ----------------
// One block per batch row b, 512 threads = one h per thread, single pass.
// (f, add, o are recomputed per-row inside update_C -- no ws round-trip.)
__global__ __launch_bounds__(512) void gate_pointwise(
    const float* __restrict__ gates, const float* __restrict__ m_prev,
    const float* __restrict__ n_prev, float* __restrict__ out,
    float* __restrict__ invden) {
  const int b = blockIdx.x;
  const int h = threadIdx.x;                       // [0, 512)
  const float inv_sqrt_h = 0.044194173824159216f;  // 1/sqrt(512)

  const float* g = gates + (size_t)b * G6;
  float* out_m = out + BH + CSZ;
  float* out_n = out_m + BH;

  const float ig = g[h];
  const float fg = g[512 + h];
  const float q  = g[1536 + h];
  const float k  = g[2048 + h];

  const int   idx = b * H_DIM + h;
  const float kt  = inv_sqrt_h * k;
  const float mp  = m_prev[idx];
  const float npv = n_prev[idx];
  const float mt  = fmaxf(fg + mp, ig);
  const float it  = expf(ig - mt);
  const float ft  = expf(fg + mp - mt);    // arg <= 0, no overflow
  const float nt  = ft * npv + it * kt;

  out_m[idx] = mt;
  out_n[idx] = nt;

  __shared__ float red[512];
  red[h] = nt * q;
  __syncthreads();
#pragma unroll
  for (int s = 256; s > 0; s >>= 1) {
    if (h < s) red[h] += red[h + s];
    __syncthreads();
  }
  if (h == 0) {
    const float denom = fmaxf(fabsf(red[0]), 1e-6f);
    invden[b] = 1.0f / denom;
  }
}

// ---------------- Kernel 3: C_t = f*C_prev + add; Cq; h_t ----------------
// 2048 blocks x 256 threads; each block owns 32 consecutive rows (same batch b
// since 32 | 512), one row per wave per iteration (8 iterations).
// Per-row scalars f, add, o recomputed from gates (wave-uniform scalar loads,
// 2 expf per row -- negligible), hoisted to block start.
// q[b,:] hoisted into registers once; C stream uses nontemporal loads/stores
// (single-use 134 MB each way -> don't churn L2).
__global__ __launch_bounds__(256) void update_C(
    const float* __restrict__ C_prev, const float* __restrict__ gates,
    const float* __restrict__ m_prev, const float* __restrict__ invden,
    float* __restrict__ out) {
  const int tid  = threadIdx.x;
  const int lane = tid & 63;
  const int w    = tid >> 6;
  const int r0   = blockIdx.x * 32;     // 32 rows per block, block-uniform b
  const int b    = r0 >> 9;
  const int i0   = r0 & 511;
  const float inv_sqrt_h = 0.044194173824159216f;  // 1/sqrt(512)

  const float* g = gates + (size_t)b * G6;
  const float4* q4 = reinterpret_cast<const float4*>(g + 1536);
  const float4 qa = q4[lane];
  const float4 qb = q4[lane + 64];
  const float inv_d = invden[b];

  // per-row scalars recomputed from gates (identical fp32 exprs as reference)
  float fv[8], av[8], hv[8];
#pragma unroll
  for (int it = 0; it < 8; ++it) {
    const int i  = i0 + it * 4 + w;
    const float ig = g[i];
    const float fg = g[512 + i];
    const float og = g[1024 + i];
    const float k  = g[2048 + i];
    const float v  = g[2560 + i];
    const float mp = m_prev[r0 + it * 4 + w];
    const float kt = inv_sqrt_h * k;
    const float mt = fmaxf(fg + mp, ig);
    const float iv = expf(ig - mt);
    fv[it] = expf(fg + mp - mt);
    av[it] = iv * v * kt;
    hv[it] = 1.0f / (1.0f + expf(-og));
  }

#pragma unroll
  for (int it = 0; it < 8; ++it) {
    const int r = r0 + it * 4 + w;
    const float f = fv[it];
    const float a = av[it];

    const f32x4* cp = reinterpret_cast<const f32x4*>(C_prev) + (size_t)r * 128;
    f32x4*       ct = reinterpret_cast<f32x4*>((float*)out + BH) + (size_t)r * 128;

    const f32x4 c0 = __builtin_nontemporal_load(cp + lane);
    const f32x4 c1 = __builtin_nontemporal_load(cp + lane + 64);

    f32x4 o0, o1;
    o0.x = f * c0.x + a;  o0.y = f * c0.y + a;
    o0.z = f * c0.z + a;  o0.w = f * c0.w + a;
    o1.x = f * c1.x + a;  o1.y = f * c1.y + a;
    o1.z = f * c1.z + a;  o1.w = f * c1.w + a;

    __builtin_nontemporal_store(o0, ct + lane);
    __builtin_nontemporal_store(o1, ct + lane + 64);

    float cq = o0.x * qa.x + o0.y * qa.y + o0.z * qa.z + o0.w * qa.w
             + o1.x * qb.x + o1.y * qb.y + o1.z * qb.z + o1.w * qb.w;
#pragma unroll
    for (int off = 32; off > 0; off >>= 1)
      cq += __shfl_xor(cq, off, 64);
    if (lane == 0)
      out[r] = hv[it] * cq * inv_d;
  }
}

extern "C" void kernel_launch(void* const* d_in, const int* in_sizes, int n_in,
                              void* d_out, int out_size, void* d_ws, size_t ws_size,
                              hipStream_t stream) {
  const float* x      = (const float*)d_in[0];
  // d_in[1] = h_prev (unused by the reference computation)
  const float* C_prev = (const float*)d_in[2];
  const float* m_prev = (const float*)d_in[3];
  const float* n_prev = (const float*)d_in[4];
  const float* W      = (const float*)d_in[5];
  const float* bias   = (const float*)d_in[6];

  float* out = (float*)d_out;
  float* ws  = (float*)d_ws;

  float* gates  = ws;
  float* invden = ws + 393216;

  gemm_gates<<<768, 128, 0, stream>>>(x, W, bias, gates);
  gate_pointwise<<<B_SZ, 512, 0, stream>>>(gates, m_prev, n_prev, out, invden);
  update_C<<<BH / 32, 256, 0, stream>>>(C_prev, gates, m_prev, invden, out);
}

// Round 5
// 273.100 us; speedup vs baseline: 1.0391x; 1.0039x over previous
//
#include <hip/hip_runtime.h>
#include <math.h>

// mLSTM cell, B=128, I=512, H=512.
// Outputs concatenated: h_t[128*512], C_t[128*512*512], m_t[128*512], n_t[128*512]
//
// ws layout (floats):
//   gates : 128*3072 = 393216 @ 0
// total ~1.5 MB

#define B_SZ   128
#define H_DIM  512
#define I_DIM  512
#define G6     3072           // 6*H
#define BH     65536          // B*H
#define CSZ    33554432       // B*H*H

// native vector type for nontemporal builtins (HIP float4 is a class -> rejected)
typedef float f32x4 __attribute__((ext_vector_type(4)));

// ---------------- Kernel 1: gates = x @ W^T + b ----------------
// 24 c-tiles x 128 columns, b-tile = 4 -> grid = 24*32 = 768 blocks x 128 thr
// (3 blocks/CU, all co-resident). XCD-aware mapping: ctile = (blk%8)*3 +
// (blk/8)%3 pins 3 c-tiles (768 KB of W) to each XCD -> the 32x b-tile
// re-reads of each W c-tile hit that XCD's 4 MiB L2 instead of LLC.
// x addresses are wave-uniform -> scalar loads; W is per-thread sequential float4.
__global__ __launch_bounds__(128) void gemm_gates(
    const float* __restrict__ x, const float* __restrict__ W,
    const float* __restrict__ bias, float* __restrict__ gates) {
  const int tid   = threadIdx.x;
  const int blk   = blockIdx.x;
  const int xcd   = blk & 7;
  const int j     = blk >> 3;            // [0, 96)
  const int ctile = xcd * 3 + (j % 3);   // [0, 24) -- 3 c-tiles per XCD
  const int btile = j / 3;               // [0, 32)
  const int c     = ctile * 128 + tid;   // [0, 3072)
  const int b0    = btile * 4;           // [0, 128) step 4

  float acc[4];
#pragma unroll
  for (int jj = 0; jj < 4; ++jj) acc[jj] = 0.0f;

  const float4* wrow = reinterpret_cast<const float4*>(W + (size_t)c * I_DIM);
  const float4* x4   = reinterpret_cast<const float4*>(x);

#pragma unroll 4
  for (int t4 = 0; t4 < I_DIM / 4; ++t4) {
    const float4 wv = wrow[t4];
#pragma unroll
    for (int jj = 0; jj < 4; ++jj) {
      const float4 xv = x4[(b0 + jj) * (I_DIM / 4) + t4];  // uniform -> s_load
      acc[jj] += xv.x * wv.x + xv.y * wv.y + xv.z * wv.z + xv.w * wv.w;
    }
  }
  const float bi = bias[c];
#pragma unroll
  for (int jj = 0; jj < 4; ++jj)
    gates[(size_t)(b0 + jj) * G6 + c] = acc[jj] + bi;  // coalesced over c
}

// ---------------- Kernel 2: everything else, fused ----------------
// 2048 blocks x 256 threads; each block owns 32 consecutive rows of ONE batch
// b (32 | 512). Per block:
//   1. redundantly compute the full 512-term n_t*q reduction for its b
//      (2 pointwise terms/thread, L2-hot loads; LDS tree bitwise-identical in
//      order to the old 512-thread kernel's tree) -> invden locally, no
//      workspace round-trip, no third launch.
//   2. write m_t/n_t for its own 32 rows only (non-redundant).
//   3. stream C: C_t = f*C_prev + add (nontemporal, single-use 134 MB each
//      way), fused dot with q -> h_t = o * Cq * invden.
__global__ __launch_bounds__(256) void update_C(
    const float* __restrict__ C_prev, const float* __restrict__ gates,
    const float* __restrict__ m_prev, const float* __restrict__ n_prev,
    float* __restrict__ out) {
  const int tid  = threadIdx.x;
  const int lane = tid & 63;
  const int w    = tid >> 6;
  const int r0   = blockIdx.x * 32;     // 32 rows per block, block-uniform b
  const int b    = r0 >> 9;
  const int i0   = r0 & 511;
  const float inv_sqrt_h = 0.044194173824159216f;  // 1/sqrt(512)

  const float* g = gates + (size_t)b * G6;

  // ---- pointwise terms for h = tid and h = tid+256 ----
  const int h0 = tid, h1 = tid + 256;
  const float ig0 = g[h0],        ig1 = g[h1];
  const float fg0 = g[512 + h0],  fg1 = g[512 + h1];
  const float q0  = g[1536 + h0], q1  = g[1536 + h1];
  const float k0  = g[2048 + h0], k1  = g[2048 + h1];
  const float mp0 = m_prev[b * H_DIM + h0], mp1 = m_prev[b * H_DIM + h1];
  const float np0 = n_prev[b * H_DIM + h0], np1 = n_prev[b * H_DIM + h1];

  const float kt0 = inv_sqrt_h * k0,        kt1 = inv_sqrt_h * k1;
  const float mt0 = fmaxf(fg0 + mp0, ig0),  mt1 = fmaxf(fg1 + mp1, ig1);
  const float it0 = expf(ig0 - mt0),        it1 = expf(ig1 - mt1);
  const float ft0 = expf(fg0 + mp0 - mt0),  ft1 = expf(fg1 + mp1 - mt1);
  const float nt0 = ft0 * np0 + it0 * kt0,  nt1 = ft1 * np1 + it1 * kt1;

  // m_t / n_t written by the owning block only (rows [i0, i0+32))
  float* out_m = out + BH + CSZ;
  float* out_n = out_m + BH;
  if ((unsigned)(h0 - i0) < 32u) {
    out_m[b * H_DIM + h0] = mt0;
    out_n[b * H_DIM + h0] = nt0;
  }
  if ((unsigned)(h1 - i0) < 32u) {
    out_m[b * H_DIM + h1] = mt1;
    out_n[b * H_DIM + h1] = nt1;
  }

  // ---- 512-term nq reduction (order identical to old 512-thread tree) ----
  __shared__ float red[256];
  red[tid] = nt0 * q0 + nt1 * q1;   // == old tree's first step (s=256)
  __syncthreads();
#pragma unroll
  for (int s = 128; s > 0; s >>= 1) {
    if (tid < s) red[tid] += red[tid + s];
    __syncthreads();
  }
  const float inv_d = 1.0f / fmaxf(fabsf(red[0]), 1e-6f);

  // ---- per-row scalars for this wave's 8 C-rows (wave-uniform loads) ----
  float fv[8], av[8], hv[8];
#pragma unroll
  for (int it = 0; it < 8; ++it) {
    const int i  = i0 + it * 4 + w;
    const float ig = g[i];
    const float fg = g[512 + i];
    const float og = g[1024 + i];
    const float k  = g[2048 + i];
    const float v  = g[2560 + i];
    const float mp = m_prev[r0 + it * 4 + w];
    const float kt = inv_sqrt_h * k;
    const float mt = fmaxf(fg + mp, ig);
    const float iv = expf(ig - mt);
    fv[it] = expf(fg + mp - mt);
    av[it] = iv * v * kt;
    hv[it] = 1.0f / (1.0f + expf(-og));
  }

  const float4* q4 = reinterpret_cast<const float4*>(g + 1536);
  const float4 qa = q4[lane];
  const float4 qb = q4[lane + 64];

  // ---- C stream ----
#pragma unroll
  for (int it = 0; it < 8; ++it) {
    const int r = r0 + it * 4 + w;
    const float f = fv[it];
    const float a = av[it];

    const f32x4* cp = reinterpret_cast<const f32x4*>(C_prev) + (size_t)r * 128;
    f32x4*       ct = reinterpret_cast<f32x4*>((float*)out + BH) + (size_t)r * 128;

    const f32x4 c0 = __builtin_nontemporal_load(cp + lane);
    const f32x4 c1 = __builtin_nontemporal_load(cp + lane + 64);

    f32x4 o0, o1;
    o0.x = f * c0.x + a;  o0.y = f * c0.y + a;
    o0.z = f * c0.z + a;  o0.w = f * c0.w + a;
    o1.x = f * c1.x + a;  o1.y = f * c1.y + a;
    o1.z = f * c1.z + a;  o1.w = f * c1.w + a;

    __builtin_nontemporal_store(o0, ct + lane);
    __builtin_nontemporal_store(o1, ct + lane + 64);

    float cq = o0.x * qa.x + o0.y * qa.y + o0.z * qa.z + o0.w * qa.w
             + o1.x * qb.x + o1.y * qb.y + o1.z * qb.z + o1.w * qb.w;
#pragma unroll
    for (int off = 32; off > 0; off >>= 1)
      cq += __shfl_xor(cq, off, 64);
    if (lane == 0)
      out[r] = hv[it] * cq * inv_d;
  }
}

extern "C" void kernel_launch(void* const* d_in, const int* in_sizes, int n_in,
                              void* d_out, int out_size, void* d_ws, size_t ws_size,
                              hipStream_t stream) {
  const float* x      = (const float*)d_in[0];
  // d_in[1] = h_prev (unused by the reference computation)
  const float* C_prev = (const float*)d_in[2];
  const float* m_prev = (const float*)d_in[3];
  const float* n_prev = (const float*)d_in[4];
  const float* W      = (const float*)d_in[5];
  const float* bias   = (const float*)d_in[6];

  float* out   = (float*)d_out;
  float* gates = (float*)d_ws;

  gemm_gates<<<768, 128, 0, stream>>>(x, W, bias, gates);
  update_C<<<BH / 32, 256, 0, stream>>>(C_prev, gates, m_prev, n_prev, out);
}